// Round 8
// baseline (187.571 us; speedup 1.0000x reference)
//
#include <hip/hip_runtime.h>
#include <hip/hip_bf16.h>

// Swin3D MHSA: B=256 windows, N=392 tokens, DIM=128, H=4 heads, dh=32.
// R8: mega-kernel attention PV now uses mfma_f32_16x16x16bf16_1k so the
//     P matrix stays in registers (A-fragment layout matches the swapped-QK^T
//     output exactly) -> the per-g LDS write/wait/read round-trip is GONE.
//     Bias vectors prefetched into registers per rb. W-frag loads shared
//     across both m-tiles in the QKV phase.

typedef __attribute__((ext_vector_type(8))) short bf16x8;
typedef __attribute__((ext_vector_type(4))) float f32x4;
typedef __attribute__((ext_vector_type(4))) short s16x4;
typedef __attribute__((ext_vector_type(2))) unsigned int u32x2;

#define NTOK 392
#define NN (NTOK * NTOK)   // 153664
#define TABLE 2535         // 15*13*13
#define SCALE 0.17677669529663689f  // 1/sqrt(32)

__device__ __forceinline__ unsigned short f2bf(float f) {
  union { float f; unsigned u; } v; v.f = f;
  unsigned r = v.u + 0x7FFFu + ((v.u >> 16) & 1u);
  return (unsigned short)(r >> 16);
}
__device__ __forceinline__ float b2f(short s) {
  union { unsigned u; float f; } v;
  v.u = ((unsigned)(unsigned short)s) << 16;
  return v.f;
}
__device__ __forceinline__ unsigned pk2(float lo, float hi) {
  return (unsigned)f2bf(lo) | ((unsigned)f2bf(hi) << 16);
}

// ---------------- K0: one-time weight conversion f32 -> bf16 ----------------
__global__ __launch_bounds__(256) void wcvt_kernel(
    const float* __restrict__ Wqkv, const float* __restrict__ Wp,
    unsigned short* __restrict__ wqbf, unsigned short* __restrict__ wpbf) {
  int g = blockIdx.x * 256 + threadIdx.x;  // 16384 threads x 4 elems
  const float* src; unsigned short* dst; int off;
  if (g < 12288) { src = Wqkv; dst = wqbf; off = g * 4; }
  else           { src = Wp;   dst = wpbf; off = (g - 12288) * 4; }
  f32x4 v = *(const f32x4*)(src + off);
  s16x4 o;
  o[0] = (short)f2bf(v[0]); o[1] = (short)f2bf(v[1]);
  o[2] = (short)f2bf(v[2]); o[3] = (short)f2bf(v[3]);
  *(s16x4*)(dst + off) = o;
}

// ---------------- K1: bias in MFMA lane layout ----------------
__global__ __launch_bounds__(256) void biaspre_kernel(
    const float* __restrict__ rpb, const int* __restrict__ relidx,
    unsigned short* __restrict__ biaspre) {
  int g = blockIdx.x * 256 + threadIdx.x;  // 4*25*25*256 = 640000
  if (g >= 640000) return;
  int r = g & 3, lane = (g >> 2) & 63;
  int t = g >> 8;
  int jt = t % 25; int t2 = t / 25;
  int rb = t2 % 25; int h = t2 / 25;
  int q = rb * 16 + (lane & 15); if (q > 391) q = 391;
  int k = jt * 16 + (lane >> 4) * 4 + r; if (k > 391) k = 391;
  int f = q * (NTOK * 4) + k * 4 + h;   // raw (n,n,H) reshape quirk
  int hs = f / NN; int p = f - hs * NN;
  biaspre[g] = f2bf(rpb[hs * TABLE + relidx[p]]);
}

// ---------------- K2: MEGA — fused QKV + attention ----------------
// 1 block per window, 1024 threads = 16 waves; wave w owns m-tiles {w, w+16}.
__global__ __launch_bounds__(1024, 4) void mega_kernel(
    const float* __restrict__ hidden, const unsigned short* __restrict__ wqbf,
    const float* __restrict__ bqkv, const unsigned short* __restrict__ biaspre,
    unsigned short* __restrict__ ctxbuf) {
  __shared__ unsigned short Ksh[400][40];     // 32000 B
  __shared__ unsigned short Vtsh[32][424];    // 27136 B
  __shared__ unsigned short WB[16][16][40];   // 20480 B per-wave Q-transpose
                                              // total 79616 B

  const int tid = threadIdx.x;                // 0..1023
  const int w = tid >> 6, lane = tid & 63;
  const int l15 = lane & 15, lhi = lane >> 4;
  const int b = blockIdx.x;

  // zero pads once: Ksh rows 392..399 (all 40 cols); Vtsh cols 392..423 x 32 rows
  if (tid < 512) { int r = tid >> 6, c = tid & 63; if (c < 40) Ksh[392 + r][c] = 0; }
  Vtsh[tid >> 5][392 + (tid & 31)] = 0;

  const float* hwin = hidden + (size_t)b * NTOK * 128;

  // ---- A fragments: loaded + converted ONCE (i=1 clamped to tile 24 for w>=9,
  //      its results are discarded at store time) ----
  const int mtc[2] = {w, (w + 16 < 25) ? (w + 16) : 24};
  bf16x8 afr[2][4];
#pragma unroll
  for (int i = 0; i < 2; ++i) {
    int arow = mtc[i] * 16 + l15; if (arow > 391) arow = 391;
#pragma unroll
    for (int kk = 0; kk < 4; ++kk) {
      const float* ap = hwin + (size_t)arow * 128 + kk * 32 + lhi * 8;
      f32x4 lo = *(const f32x4*)ap;
      f32x4 hi = *(const f32x4*)(ap + 4);
      bf16x8 a;
      a[0] = (short)f2bf(lo[0]); a[1] = (short)f2bf(lo[1]);
      a[2] = (short)f2bf(lo[2]); a[3] = (short)f2bf(lo[3]);
      a[4] = (short)f2bf(hi[0]); a[5] = (short)f2bf(hi[1]);
      a[6] = (short)f2bf(hi[2]); a[7] = (short)f2bf(hi[3]);
      afr[i][kk] = a;
    }
  }
  const bool has1 = (w + 16 < 25);

  for (int h = 0; h < 4; ++h) {
    __syncthreads();  // h=0: covers pad init; h>0: prev attn done reading LDS

    float bq[2], bk[2], bv[2];
#pragma unroll
    for (int jt = 0; jt < 2; ++jt) {
      int d = h * 32 + jt * 16 + l15;
      bq[jt] = bqkv[d]; bk[jt] = bqkv[128 + d]; bv[jt] = bqkv[256 + d];
    }

    bf16x8 qreg[2];
#pragma unroll
    for (int ss = 0; ss < 3; ++ss) {
      // W fragments loaded once, shared by both m-tiles
      f32x4 ac[2][2];
      ac[0][0] = 0.0f; ac[0][1] = 0.0f; ac[1][0] = 0.0f; ac[1][1] = 0.0f;
#pragma unroll
      for (int kk = 0; kk < 4; ++kk) {
        const unsigned short* wp0 =
            wqbf + ((size_t)(ss * 128 + h * 32 + l15)) * 128 + kk * 32 + lhi * 8;
        bf16x8 wf0 = *(const bf16x8*)wp0;
        bf16x8 wf1 = *(const bf16x8*)(wp0 + 16 * 128);
        ac[0][0] = __builtin_amdgcn_mfma_f32_16x16x32_bf16(afr[0][kk], wf0, ac[0][0], 0, 0, 0);
        ac[0][1] = __builtin_amdgcn_mfma_f32_16x16x32_bf16(afr[0][kk], wf1, ac[0][1], 0, 0, 0);
        ac[1][0] = __builtin_amdgcn_mfma_f32_16x16x32_bf16(afr[1][kk], wf0, ac[1][0], 0, 0, 0);
        ac[1][1] = __builtin_amdgcn_mfma_f32_16x16x32_bf16(afr[1][kk], wf1, ac[1][1], 0, 0, 0);
      }
#pragma unroll
      for (int i = 0; i < 2; ++i) {
        if (i == 1 && !has1) break;   // discard clamped duplicate
        const int tok0 = mtc[i] * 16 + lhi * 4;
        if (ss == 0) {
#pragma unroll
          for (int r = 0; r < 4; ++r) {
            WB[w][lhi * 4 + r][l15]      = f2bf((ac[i][0][r] + bq[0]) * SCALE);
            WB[w][lhi * 4 + r][16 + l15] = f2bf((ac[i][1][r] + bq[1]) * SCALE);
          }
          qreg[i] = *(const bf16x8*)&WB[w][l15][lhi * 8];
        } else if (ss == 1) {
#pragma unroll
          for (int r = 0; r < 4; ++r) {
            int t = tok0 + r;
            if (t < NTOK) {
              Ksh[t][l15]      = f2bf(ac[i][0][r] + bk[0]);
              Ksh[t][16 + l15] = f2bf(ac[i][1][r] + bk[1]);
            }
          }
        } else {
          if (tok0 < NTOK) {
            u32x2 pv;
            pv[0] = pk2(ac[i][0][0] + bv[0], ac[i][0][1] + bv[0]);
            pv[1] = pk2(ac[i][0][2] + bv[0], ac[i][0][3] + bv[0]);
            *(u32x2*)&Vtsh[l15][tok0] = pv;
            pv[0] = pk2(ac[i][1][0] + bv[1], ac[i][1][1] + bv[1]);
            pv[1] = pk2(ac[i][1][2] + bv[1], ac[i][1][3] + bv[1]);
            *(u32x2*)&Vtsh[16 + l15][tok0] = pv;
          }
        }
      }
    }
    __syncthreads();

    // ---- attention for head h: QK^T (K=32) -> exp -> PV (K=16, P in regs) ----
    const s16x4* bias_lane =
        (const s16x4*)(biaspre + (size_t)h * 25 * 25 * 256 + (size_t)lane * 4);

#pragma unroll
    for (int i = 0; i < 2; ++i) {
      if (i == 1 && !has1) continue;
      const int rb = mtc[i];
      bf16x8 qf = qreg[i];
      const s16x4* bp = bias_lane + (size_t)rb * 25 * 64;

      // prefetch all 25 bias vectors into registers
      s16x4 bias_r[25];
#pragma unroll
      for (int jt = 0; jt < 25; ++jt) bias_r[jt] = bp[jt * 64];

      f32x4 o0 = 0.0f, o1 = 0.0f;
      float ssum = 0.f;

#pragma unroll
      for (int jt = 0; jt < 25; ++jt) {
        bf16x8 kf = *(const bf16x8*)&Ksh[jt * 16 + l15][lhi * 8];
        f32x4 s = __builtin_amdgcn_mfma_f32_16x16x32_bf16(kf, qf, (f32x4)0.f, 0, 0, 0);
        float e0 = __expf(s[0] + b2f(bias_r[jt][0]));
        float e1 = __expf(s[1] + b2f(bias_r[jt][1]));
        float e2 = __expf(s[2] + b2f(bias_r[jt][2]));
        float e3 = __expf(s[3] + b2f(bias_r[jt][3]));
        if (jt == 24 && lhi >= 2) { e0 = 0.f; e1 = 0.f; e2 = 0.f; e3 = 0.f; }
        ssum += (e0 + e1) + (e2 + e3);
        s16x4 pa;
        pa[0] = (short)f2bf(e0); pa[1] = (short)f2bf(e1);
        pa[2] = (short)f2bf(e2); pa[3] = (short)f2bf(e3);
        s16x4 vf0 = *(const s16x4*)&Vtsh[l15][jt * 16 + lhi * 4];
        s16x4 vf1 = *(const s16x4*)&Vtsh[16 + l15][jt * 16 + lhi * 4];
        o0 = __builtin_amdgcn_mfma_f32_16x16x16bf16_1k(pa, vf0, o0, 0, 0, 0);
        o1 = __builtin_amdgcn_mfma_f32_16x16x16bf16_1k(pa, vf1, o1, 0, 0, 0);
      }

      ssum += __shfl_xor(ssum, 16);
      ssum += __shfl_xor(ssum, 32);
      float rtot = 1.f / ssum;
      float rr[4];
#pragma unroll
      for (int r = 0; r < 4; ++r) rr[r] = __shfl(rtot, lhi * 4 + r);

#pragma unroll
      for (int r = 0; r < 4; ++r) {
        int row = rb * 16 + lhi * 4 + r;
        if (row < NTOK) {
          unsigned short* crow = ctxbuf + ((size_t)(b * NTOK) + row) * 128 + h * 32;
          crow[l15] = f2bf(o0[r] * rr[r]);
          crow[16 + l15] = f2bf(o1[r] * rr[r]);
        }
      }
    }
  }
}

// ---------------- K3: output projection — streaming, nt stores -------------
__global__ __launch_bounds__(256, 4) void proj_kernel(
    const unsigned short* __restrict__ ctxbuf, const unsigned short* __restrict__ wpbf,
    const float* __restrict__ bp, float* __restrict__ out) {
  const int tid = threadIdx.x;
  const int w = tid >> 6, lane = tid & 63, l15 = lane & 15, lhi = lane >> 4;
  const int trow = blockIdx.x * 64 + w * 16;

  bf16x8 af[4];
#pragma unroll
  for (int kk = 0; kk < 4; ++kk)
    af[kk] = *(const bf16x8*)(
        ctxbuf + ((size_t)(trow + l15)) * 128 + kk * 32 + lhi * 8);

  f32x4 acc[8];
#pragma unroll
  for (int jt = 0; jt < 8; ++jt) acc[jt] = 0.0f;
#pragma unroll
  for (int kk = 0; kk < 4; ++kk) {
#pragma unroll
    for (int jt = 0; jt < 8; ++jt) {
      bf16x8 wf = *(const bf16x8*)(
          wpbf + ((size_t)(jt * 16 + l15)) * 128 + kk * 32 + lhi * 8);
      acc[jt] = __builtin_amdgcn_mfma_f32_16x16x32_bf16(af[kk], wf, acc[jt], 0, 0, 0);
    }
  }
#pragma unroll
  for (int jt = 0; jt < 8; ++jt) {
    int colL = jt * 16 + l15;
    float bias = bp[colL];
#pragma unroll
    for (int r = 0; r < 4; ++r) {
      int t = trow + lhi * 4 + r;
      __builtin_nontemporal_store(acc[jt][r] + bias, &out[(size_t)t * 128 + colL]);
    }
  }
}

// ---------------- launch ----------------
extern "C" void kernel_launch(void* const* d_in, const int* in_sizes, int n_in,
                              void* d_out, int out_size, void* d_ws, size_t ws_size,
                              hipStream_t stream) {
  const float* hidden = (const float*)d_in[0];
  const float* Wqkv = (const float*)d_in[1];
  const float* bqkv = (const float*)d_in[2];
  const float* Wp = (const float*)d_in[3];
  const float* bp = (const float*)d_in[4];
  const float* rpb = (const float*)d_in[5];
  const int* relidx = (const int*)d_in[6];

  // ws: ctx (12,845,056 bf16) | biaspre (640,000) | wq_bf (49,152) | wp_bf (16,384)
  unsigned short* ctxbuf = (unsigned short*)d_ws;
  unsigned short* biaspre = ctxbuf + 12845056;
  unsigned short* wqbf = biaspre + 640000;
  unsigned short* wpbf = wqbf + 49152;

  wcvt_kernel<<<64, 256, 0, stream>>>(Wqkv, Wp, wqbf, wpbf);
  biaspre_kernel<<<2500, 256, 0, stream>>>(rpb, relidx, biaspre);
  mega_kernel<<<256, 1024, 0, stream>>>(hidden, wqbf, bqkv, biaspre, ctxbuf);
  proj_kernel<<<1568, 256, 0, stream>>>(ctxbuf, wpbf, bp, (float*)d_out);
}